// Round 12
// baseline (30.755 us; speedup 1.0000x reference)
//
#include <hip/hip_runtime.h>
#include <math.h>

// Problem constants (from reference: x = (2,2,160,160,160) fp32)
#define BCn 4
#define Dn 160
#define Hn 160
#define Wn 160
#define HWn (Hn * Wn)
#define W4q (Wn / 4)        // 40 float4 groups per row
#define COLS (Hn * W4q)     // 6400 (h, q) columns per plane
#define DCHUNK 5
#define NZC (Dn / DCHUNK)   // 32 z-chunks
#define XBLK (COLS / 256)   // 25 x-blocks per work-row
#define BLOCK 256
#define HALO 41             // 40 (h-row) + 1 (w corner) col4 halo each side
#define STG (BLOCK + 2 * HALO)  // 338 staged col4 groups per plane

// Native clang vector for __builtin_nontemporal_store (HIP float4 rejected).
typedef float f32x4 __attribute__((ext_vector_type(4)));

// Reduced per-plane state:
//   Rs = 3x3 window sums (gd), Rd = row diffs (gh), Cs = col diffs (gw).
struct Plane {
  float4 Rs, Rd, Cs;
};

__device__ __forceinline__ f32x4 mag4(const Plane& P0, const Plane& P1,
                                      const Plane& P2) {
  const float gdx = P2.Rs.x - P0.Rs.x;
  const float gdy = P2.Rs.y - P0.Rs.y;
  const float gdz = P2.Rs.z - P0.Rs.z;
  const float gdw = P2.Rs.w - P0.Rs.w;
  const float ghx = P0.Rd.x + P1.Rd.x + P2.Rd.x;
  const float ghy = P0.Rd.y + P1.Rd.y + P2.Rd.y;
  const float ghz = P0.Rd.z + P1.Rd.z + P2.Rd.z;
  const float ghw = P0.Rd.w + P1.Rd.w + P2.Rd.w;
  const float gwx = P0.Cs.x + P1.Cs.x + P2.Cs.x;
  const float gwy = P0.Cs.y + P1.Cs.y + P2.Cs.y;
  const float gwz = P0.Cs.z + P1.Cs.z + P2.Cs.z;
  const float gww = P0.Cs.w + P1.Cs.w + P2.Cs.w;
  f32x4 g;
  // Raw v_sqrt_f32 — abs threshold 0.555, libm fixup unnecessary.
  g.x = __builtin_amdgcn_sqrtf(fmaf(gdx, gdx, fmaf(ghx, ghx, gwx * gwx)));
  g.y = __builtin_amdgcn_sqrtf(fmaf(gdy, gdy, fmaf(ghy, ghy, gwy * gwy)));
  g.z = __builtin_amdgcn_sqrtf(fmaf(gdz, gdz, fmaf(ghz, ghz, gwz * gwz)));
  g.w = __builtin_amdgcn_sqrtf(fmaf(gdw, gdw, fmaf(ghw, ghw, gww * gww)));
  return g;
}

__global__ __launch_bounds__(BLOCK) void sobel3d_mag_kernel(
    const float* __restrict__ x, float* __restrict__ out) {
  // Double-buffered plane stage: each plane read ONCE from global per block
  // (3x fewer L1/L2 request bytes than the per-thread 3-row loads).
  __shared__ float4 buf[2][STG];

  // XCD-locality swizzle (R9 win): all 25 x-blocks of a work-row
  // (z-chunk, channel) share one XCD -> its planes are on-XCD L2 hits.
  const int F = blockIdx.x;          // 0..3199
  const int k = F & 7;               // xcd (hw round-robin heuristic)
  const int j = F >> 3;              // 0..399
  const int bx = j % XBLK;           // x-block within work-row
  const int wr = (j / XBLK) * 8 + k; // work-row 0..127, stays on xcd k
  const int zc_idx = wr & (NZC - 1);
  const int bc = wr >> 5;

  const int tid = threadIdx.x;
  const int base = bx * BLOCK;
  const int col4 = base + tid;       // (h, q) column, 0..6399
  const int h = col4 / W4q;
  const int q = col4 - h * W4q;
  const int w4 = q * 4;
  const int d0 = zc_idx * DCHUNK;

  const float* xb = x + (size_t)bc * Dn * HWn;
  float* ob = out + (size_t)bc * Dn * HWn;

  // Staging source columns. h-replicate (rows -1 / 160) folds into +/-40;
  // the final [0,COLS) clamp covers the two diagonal don't-care corners.
  int g0 = base - HALO + tid;
  int c0 = g0 < 0 ? g0 + W4q : (g0 >= COLS ? g0 - W4q : g0);
  c0 = c0 < 0 ? 0 : (c0 > COLS - 1 ? COLS - 1 : c0);
  int g1 = g0 + BLOCK;
  int c1 = g1 >= COLS ? g1 - W4q : g1;
  c1 = c1 > COLS - 1 ? COLS - 1 : c1;
  const bool extra = tid < (STG - BLOCK);  // first 82 threads stage 2 slots

  const int s = tid + HALO;  // own slot
  const int lane = tid & 63;
  const bool ql = (q == 0);
  const bool qr = (q == W4q - 1);

  // Stage plane zz (z-clamped) into buf[b]: 1.32 coalesced float4 loads
  // per thread instead of 3.
  auto stage = [&](int b, int zz) {
    const int zc = zz < 0 ? 0 : (zz > Dn - 1 ? Dn - 1 : zz);
    const float* p = xb + (size_t)zc * HWn;
    const float4 v0 = *(const float4*)(p + c0 * 4);
    buf[b][tid] = v0;
    if (extra) {
      const float4 v1 = *(const float4*)(p + c1 * 4);
      buf[b][tid + BLOCK] = v1;
    }
  };

  // Read 3 stencil rows from LDS and reduce to Plane. W-halo via shuffles;
  // wave-edge lanes (0/63) take their halo from LDS (always staged).
  auto rdplane = [&](int b) -> Plane {
    const float4 vm = buf[b][s - W4q];
    const float4 v0 = buf[b][s];
    const float4 vp = buf[b][s + W4q];

    float lA = __shfl_up(vm.w, 1);
    float lB = __shfl_up(v0.w, 1);
    float lC = __shfl_up(vp.w, 1);
    float rA = __shfl_down(vm.x, 1);
    float rB = __shfl_down(v0.x, 1);
    float rC = __shfl_down(vp.x, 1);
    if (lane == 0) {
      lA = buf[b][s - W4q - 1].w;
      lB = buf[b][s - 1].w;
      lC = buf[b][s + W4q - 1].w;
    }
    if (lane == 63) {
      rA = buf[b][s - W4q + 1].x;
      rB = buf[b][s + 1].x;
      rC = buf[b][s + W4q + 1].x;
    }

    // Replicate clamp at row w-edges.
    const float m0 = ql ? vm.x : lA;
    const float c0v = ql ? v0.x : lB;
    const float q0v = ql ? vp.x : lC;
    const float m5 = qr ? vm.w : rA;
    const float c5 = qr ? v0.w : rB;
    const float q5 = qr ? vp.w : rC;

    const float s0 = m0 + c0v + q0v;
    const float s1 = vm.x + v0.x + vp.x;
    const float s2 = vm.y + v0.y + vp.y;
    const float s3 = vm.z + v0.z + vp.z;
    const float s4 = vm.w + v0.w + vp.w;
    const float s5 = m5 + c5 + q5;
    const float d0v = q0v - m0;
    const float d1 = vp.x - vm.x;
    const float d2 = vp.y - vm.y;
    const float d3 = vp.z - vm.z;
    const float d4 = vp.w - vm.w;
    const float d5 = q5 - m5;

    Plane o;
    const float t12 = s1 + s2, t23 = s2 + s3, t34 = s3 + s4;
    o.Rs.x = s0 + t12;
    o.Rs.y = t12 + s3;
    o.Rs.z = t23 + s4;
    o.Rs.w = t34 + s5;
    const float u12 = d1 + d2, u23 = d2 + d3, u34 = d3 + d4;
    o.Rd.x = d0v + u12;
    o.Rd.y = u12 + d3;
    o.Rd.z = u23 + d4;
    o.Rd.w = u34 + d5;
    o.Cs.x = s2 - s0;
    o.Cs.y = s3 - s1;
    o.Cs.z = s4 - s2;
    o.Cs.w = s5 - s3;
    return o;
  };

  const int r0 = h * Wn;

  // Prime: planes d0-1, d0 into the two buffers.
  stage(0, d0 - 1);
  stage(1, d0);
  __syncthreads();
  Plane P0 = rdplane(0);
  Plane P1 = rdplane(1);
  __syncthreads();

#pragma unroll
  for (int i = 0; i < DCHUNK; ++i) {
    const int z = d0 + i;
    stage(i & 1, z + 1);  // overwrites buffer consumed 2 iters ago (safe:
                          // the intervening barrier ordered those reads)
    __syncthreads();
    Plane P2 = rdplane(i & 1);
    // Output never re-read: nontemporal store.
    __builtin_nontemporal_store(mag4(P0, P1, P2),
                                (f32x4*)(ob + (size_t)z * HWn + r0 + w4));
    P0 = P1;
    P1 = P2;
  }
}

extern "C" void kernel_launch(void* const* d_in, const int* in_sizes, int n_in,
                              void* d_out, int out_size, void* d_ws, size_t ws_size,
                              hipStream_t stream) {
  const float* x = (const float*)d_in[0];
  float* out = (float*)d_out;

  dim3 block(BLOCK);
  dim3 grid(XBLK * NZC * BCn);  // flat 3200 blocks; swizzle decoded in-kernel
  sobel3d_mag_kernel<<<grid, block, 0, stream>>>(x, out);
}

// Round 13
// 29.399 us; speedup vs baseline: 1.0461x; 1.0461x over previous
//
#include <hip/hip_runtime.h>
#include <math.h>

// Problem constants (from reference: x = (2,2,160,160,160) fp32)
#define BCn 4
#define Dn 160
#define Hn 160
#define Wn 160
#define HWn (Hn * Wn)
#define W4q (Wn / 4)        // 40 float4 groups per row
#define COLS (Hn * W4q)     // 6400 (h, q) columns per plane
#define DCHUNK 5
#define NZC (Dn / DCHUNK)   // 32 z-chunks
#define XBLK (COLS / 256)   // 25 x-blocks per work-row
#define BLOCK 256
#define GRID 2048           // 8 blocks/CU persistent
#define SLOTS (GRID / 8)    // 256 block-slots per XCD
#define ITEMS_PER_XCD (16 * XBLK)  // 16 work-rows x 25 x-blocks = 400

// Native clang vector for __builtin_nontemporal_store (HIP float4 rejected).
typedef float f32x4 __attribute__((ext_vector_type(4)));

// Reduced per-plane state:
//   Rs = 3x3 window sums (gd), Rd = row diffs (gh), Cs = col diffs (gw).
struct Plane {
  float4 Rs, Rd, Cs;
};

// One z-plane: 3 coalesced float4 loads; w-halo via neighbor-lane shuffles
// (R6 win: avoids 6 full-wave scalar loads' L1 line-touches).
__device__ __forceinline__ Plane load_plane(const float* __restrict__ xb, int zz,
                                            int rm, int r0, int rp, int w4,
                                            bool ql, bool qr, bool fixL, bool fixR) {
  const int zc = zz < 0 ? 0 : (zz > Dn - 1 ? Dn - 1 : zz);
  const float* p = xb + (size_t)zc * HWn;

  const float4 vm = *(const float4*)(p + rm + w4);
  const float4 v0 = *(const float4*)(p + r0 + w4);
  const float4 vp = *(const float4*)(p + rp + w4);

  float lA = __shfl_up(vm.w, 1);
  float lB = __shfl_up(v0.w, 1);
  float lC = __shfl_up(vp.w, 1);
  float rA = __shfl_down(vm.x, 1);
  float rB = __shfl_down(v0.x, 1);
  float rC = __shfl_down(vp.x, 1);

  if (fixL) {
    lA = p[rm + w4 - 1];
    lB = p[r0 + w4 - 1];
    lC = p[rp + w4 - 1];
  }
  if (fixR) {
    rA = p[rm + w4 + 4];
    rB = p[r0 + w4 + 4];
    rC = p[rp + w4 + 4];
  }

  const float m0 = ql ? vm.x : lA;
  const float c0 = ql ? v0.x : lB;
  const float q0 = ql ? vp.x : lC;
  const float m5 = qr ? vm.w : rA;
  const float c5 = qr ? v0.w : rB;
  const float q5 = qr ? vp.w : rC;

  const float s0 = m0 + c0 + q0;
  const float s1 = vm.x + v0.x + vp.x;
  const float s2 = vm.y + v0.y + vp.y;
  const float s3 = vm.z + v0.z + vp.z;
  const float s4 = vm.w + v0.w + vp.w;
  const float s5 = m5 + c5 + q5;
  const float d0 = q0 - m0;
  const float d1 = vp.x - vm.x;
  const float d2 = vp.y - vm.y;
  const float d3 = vp.z - vm.z;
  const float d4 = vp.w - vm.w;
  const float d5 = q5 - m5;

  Plane out;
  const float t12 = s1 + s2, t23 = s2 + s3, t34 = s3 + s4;
  out.Rs.x = s0 + t12;
  out.Rs.y = t12 + s3;
  out.Rs.z = t23 + s4;
  out.Rs.w = t34 + s5;
  const float u12 = d1 + d2, u23 = d2 + d3, u34 = d3 + d4;
  out.Rd.x = d0 + u12;
  out.Rd.y = u12 + d3;
  out.Rd.z = u23 + d4;
  out.Rd.w = u34 + d5;
  out.Cs.x = s2 - s0;
  out.Cs.y = s3 - s1;
  out.Cs.z = s4 - s2;
  out.Cs.w = s5 - s3;
  return out;
}

__device__ __forceinline__ f32x4 mag4(const Plane& P0, const Plane& P1,
                                      const Plane& P2) {
  const float gdx = P2.Rs.x - P0.Rs.x;
  const float gdy = P2.Rs.y - P0.Rs.y;
  const float gdz = P2.Rs.z - P0.Rs.z;
  const float gdw = P2.Rs.w - P0.Rs.w;
  const float ghx = P0.Rd.x + P1.Rd.x + P2.Rd.x;
  const float ghy = P0.Rd.y + P1.Rd.y + P2.Rd.y;
  const float ghz = P0.Rd.z + P1.Rd.z + P2.Rd.z;
  const float ghw = P0.Rd.w + P1.Rd.w + P2.Rd.w;
  const float gwx = P0.Cs.x + P1.Cs.x + P2.Cs.x;
  const float gwy = P0.Cs.y + P1.Cs.y + P2.Cs.y;
  const float gwz = P0.Cs.z + P1.Cs.z + P2.Cs.z;
  const float gww = P0.Cs.w + P1.Cs.w + P2.Cs.w;
  f32x4 g;
  // Raw v_sqrt_f32 — abs threshold 0.555, libm fixup unnecessary.
  g.x = __builtin_amdgcn_sqrtf(fmaf(gdx, gdx, fmaf(ghx, ghx, gwx * gwx)));
  g.y = __builtin_amdgcn_sqrtf(fmaf(gdy, gdy, fmaf(ghy, ghy, gwy * gwy)));
  g.z = __builtin_amdgcn_sqrtf(fmaf(gdz, gdz, fmaf(ghz, ghz, gwz * gwz)));
  g.w = __builtin_amdgcn_sqrtf(fmaf(gdw, gdw, fmaf(ghw, ghw, gww * gww)));
  return g;
}

__global__ __launch_bounds__(BLOCK) void sobel3d_mag_kernel(
    const float* __restrict__ x, float* __restrict__ out) {
  // Persistent blocks: 8 blocks/CU resident for the whole kernel (32
  // waves/CU = the cap). Each block consumes only work items of ITS XCD
  // (bid % 8, the same hw round-robin heuristic as the R9 swizzle), so the
  // R9 L2-locality win is preserved while dispatch/drain gaps between
  // short-lived blocks disappear.
  const int bid = blockIdx.x;
  const int k = bid & 7;             // this block's xcd
  const int slot = bid >> 3;         // 0..255 within xcd

  const int tid = threadIdx.x;
  const int lane = tid & 63;

  for (int it = slot; it < ITEMS_PER_XCD; it += SLOTS) {
    const int wrl = it / XBLK;       // 0..15: local work-row on this xcd
    const int bx = it - wrl * XBLK;  // x-block within work-row
    const int wr = wrl * 8 + k;      // global work-row 0..127
    const int zc_idx = wr & (NZC - 1);
    const int bc = wr >> 5;

    const int col4 = bx * BLOCK + tid;  // (h, q), 0..6399
    const int h = col4 / W4q;
    const int q = col4 - h * W4q;
    const int w4 = q * 4;
    const int d0 = zc_idx * DCHUNK;

    const float* xb = x + (size_t)bc * Dn * HWn;
    float* ob = out + (size_t)bc * Dn * HWn;

    const int hm = (h > 0) ? h - 1 : 0;
    const int hp = (h < Hn - 1) ? h + 1 : Hn - 1;
    const int rm = hm * Wn;
    const int r0 = h * Wn;
    const int rp = hp * Wn;

    const bool ql = (q == 0);
    const bool qr = (q == W4q - 1);
    const bool fixL = (lane == 0) && !ql;
    const bool fixR = (lane == 63) && !qr;

    Plane P0 = load_plane(xb, d0 - 1, rm, r0, rp, w4, ql, qr, fixL, fixR);
    Plane P1 = load_plane(xb, d0, rm, r0, rp, w4, ql, qr, fixL, fixR);

#pragma unroll
    for (int i = 0; i < DCHUNK; ++i) {
      const int z = d0 + i;
      Plane P2 = load_plane(xb, z + 1, rm, r0, rp, w4, ql, qr, fixL, fixR);
      // Output never re-read: nontemporal store.
      __builtin_nontemporal_store(mag4(P0, P1, P2),
                                  (f32x4*)(ob + (size_t)z * HWn + r0 + w4));
      P0 = P1;
      P1 = P2;
    }
  }
}

extern "C" void kernel_launch(void* const* d_in, const int* in_sizes, int n_in,
                              void* d_out, int out_size, void* d_ws, size_t ws_size,
                              hipStream_t stream) {
  const float* x = (const float*)d_in[0];
  float* out = (float*)d_out;

  dim3 block(BLOCK);
  dim3 grid(GRID);  // persistent: 8 blocks/CU, grid-stride over work items
  sobel3d_mag_kernel<<<grid, block, 0, stream>>>(x, out);
}